// Round 7
// baseline (303.368 us; speedup 1.0000x reference)
//
#include <hip/hip_runtime.h>
#include <stdint.h>

typedef unsigned short u16;
typedef __bf16 bf16_t;
typedef bf16_t bf16x8 __attribute__((ext_vector_type(8)));
typedef float f32x4 __attribute__((ext_vector_type(4)));
typedef u16 u16x4 __attribute__((ext_vector_type(4)));
typedef u16 u16x8 __attribute__((ext_vector_type(8)));

__device__ __forceinline__ u16 f2bf(float f) {
  union { float f; uint32_t u; } v;
  v.f = f;
  uint32_t u = v.u + 0x7fffu + ((v.u >> 16) & 1u);
  return (u16)(u >> 16);
}

__device__ __forceinline__ void gload16(const void* g, void* l) {
  __builtin_amdgcn_global_load_lds(
      (__attribute__((address_space(1))) void*)g,
      (__attribute__((address_space(3))) void*)l, 16, 0, 0);
}

__device__ __forceinline__ f32x4 mfma16(bf16x8 a, bf16x8 b, f32x4 c) {
  return __builtin_amdgcn_mfma_f32_16x16x32_bf16(a, b, c, 0, 0, 0);
}

// ---------------- fp32 -> bf16 convert ----------------
__global__ void cvt_f32_bf16(const float* __restrict__ in, u16* __restrict__ out, int n4) {
  int i = blockIdx.x * blockDim.x + threadIdx.x;
  int stride = gridDim.x * blockDim.x;
  for (; i < n4; i += stride) {
    float4 v = *((const float4*)in + i);
    u16x4 o;
    o.x = f2bf(v.x); o.y = f2bf(v.y); o.z = f2bf(v.z); o.w = f2bf(v.w);
    *((u16x4*)out + i) = o;
  }
}

// ---------------- weight transpose + convert: Wt[n][k] = (bf16)W[k][n] ----------------
__global__ void wt_transpose(const float* __restrict__ Wq, const float* __restrict__ Wk,
                             const float* __restrict__ Wv, u16* __restrict__ Oq,
                             u16* __restrict__ Ok, u16* __restrict__ Ov) {
  const float* W = blockIdx.z == 0 ? Wq : (blockIdx.z == 1 ? Wk : Wv);
  u16* O = blockIdx.z == 0 ? Oq : (blockIdx.z == 1 ? Ok : Ov);
  __shared__ float t[32][33];
  int x = threadIdx.x, y = threadIdx.y;
  int n0 = blockIdx.x * 32, k0 = blockIdx.y * 32;
#pragma unroll
  for (int i = 0; i < 32; i += 8)
    t[y + i][x] = W[(size_t)(k0 + y + i) * 1024 + n0 + x];
  __syncthreads();
#pragma unroll
  for (int i = 0; i < 32; i += 8)
    O[(size_t)(n0 + y + i) * 1024 + k0 + x] = f2bf(t[x][y + i]);
}

// ---------------- 256x256 8-phase bf16 GEMM ----------
// 512 threads = 8 waves (2M x 4N). BK=64, double-buffered LDS (128 KiB).
// EPI = 0: C = A*Bt^T + biasCol (bf16 or f32 out), optional biasRow.
// EPI = 1: P = exp2(acc*C1 + mask*C2)  (no-max softmax numerator, bf16 out).
// EPI = 2: O = acc / rowsum(A)  (PV normalize; rowsum accumulated in-register
//          from the A fragments as they stream through the K-loop).
template <typename CT, int EPI>
__global__ __launch_bounds__(512, 2) void gemm256(
    const u16* __restrict__ A, const u16* __restrict__ Bt,
    const float* __restrict__ bc0, const float* __restrict__ bc1,
    const float* __restrict__ biasRow, const float* __restrict__ Mk,
    CT* __restrict__ C, int K, int lda, int ldb, int ldc,
    long long bsA, long long bsB, long long bsC, long long bsM) {
  constexpr int MF = 8, MH = 4;
  const float C1 = 0.04508422f;    // log2(e)/32
  const float C2 = -1.4426950e9f;  // -1e9*log2(e)
  // XCD-aware chunked swizzle (T1) over the flattened grid (all grids %8==0)
  int nx = gridDim.x, ny = gridDim.y;
  int lin = blockIdx.x + nx * (blockIdx.y + ny * blockIdx.z);
  int q = (nx * ny * gridDim.z) >> 3;
  int s = (lin & 7) * q + (lin >> 3);
  int bx = s % nx, by = (s / nx) % ny, bz = s / (nx * ny);

  A += (size_t)bz * bsA;
  Bt += (size_t)bz * bsB;
  C += (size_t)bz * bsC;
  if (EPI == 1) Mk += (size_t)bz * bsM;
  const float* biasCol = (bz == 1) ? bc1 : bc0;

  __shared__ u16 aLds[2][256 * 64];
  __shared__ u16 bLds[2][256 * 64];
  int tid = threadIdx.x;
  int lane = tid & 63, w = tid >> 6;
  int l15 = lane & 15, g = lane >> 4;
  int wr = w >> 2, wc = w & 3;
  int bm = bx * 256, bn = by * 256;
  int NT = K >> 6;

  f32x4 acc[MF][4] = {};
  float rs[MF];
#pragma unroll
  for (int i = 0; i < MF; ++i) rs[i] = 0.0f;

  auto stageA = [&](int buf, int h, int tk) {
    int k0 = tk * 64;
    int r = tid >> 3, cd = (tid & 7) * 8;
    int cs = cd ^ ((r & 7) * 8);
    int row0 = h * 64 + r;
    gload16(A + (size_t)(bm + row0) * lda + k0 + cs, &aLds[buf][row0 * 64 + cd]);
    int row1 = row0 + 128;
    gload16(A + (size_t)(bm + row1) * lda + k0 + cs, &aLds[buf][row1 * 64 + cd]);
  };
  auto stageB = [&](int buf, int x, int tk) {
    int k0 = tk * 64;
#pragma unroll
    for (int l = 0; l < 2; ++l) {
      int u = l * 512 + tid;
      int r = u >> 3, cd = (u & 7) * 8;
      int cs = cd ^ ((r & 7) * 8);
      int row = x * 128 + r;
      gload16(Bt + (size_t)(bn + row) * ldb + k0 + cs, &bLds[buf][row * 64 + cd]);
    }
  };
  auto ldA = [&](int buf, int m, int kc) -> bf16x8 {
    int row = wr * 128 + m * 16 + l15;
    int col = (kc * 32 + g * 8) ^ ((row & 7) * 8);
    return *(const bf16x8*)&aLds[buf][row * 64 + col];
  };
  auto ldB = [&](int buf, int j, int kc) -> bf16x8 {
    int row = wc * 64 + j * 16 + l15;
    int col = (kc * 32 + g * 8) ^ ((row & 7) * 8);
    return *(const bf16x8*)&bLds[buf][row * 64 + col];
  };

  // prologue: issue order A0(0),B0(0),B1(0),A1(0),A0(1),B0(1)
  stageA(0, 0, 0);
  stageB(0, 0, 0);
  stageB(0, 1, 0);
  stageA(0, 1, 0);
  int t1c = NT > 1 ? 1 : 0;
  stageA(1, 0, t1c);
  stageB(1, 0, t1c);
  asm volatile("s_waitcnt vmcnt(6)" ::: "memory");
  __builtin_amdgcn_s_barrier();

  for (int t = 0; t < NT; ++t) {
    int cur = t & 1, nxt = cur ^ 1;
    int tn1 = (t + 1 < NT) ? t + 1 : NT - 1;
    int tn2 = (t + 2 < NT) ? t + 2 : NT - 1;
    bf16x8 ac[MH], ad[MH], b0[4], b1[4];

    // ---- ph1: MFMA (group0, kc0); prefetch f2 = (group0 kc1, B kc1) ----
#pragma unroll
    for (int i = 0; i < MH; ++i) ac[i] = ldA(cur, i, 0);
#pragma unroll
    for (int j = 0; j < 4; ++j) b0[j] = ldB(cur, j, 0);
    stageB(nxt, 1, tn1);
    __builtin_amdgcn_s_barrier();
#pragma unroll
    for (int i = 0; i < MH; ++i) ad[i] = ldA(cur, i, 1);
#pragma unroll
    for (int j = 0; j < 4; ++j) b1[j] = ldB(cur, j, 1);
    asm volatile("s_waitcnt lgkmcnt(8)" ::: "memory");
    __builtin_amdgcn_sched_barrier(0);
    __builtin_amdgcn_s_setprio(1);
#pragma unroll
    for (int i = 0; i < MH; ++i)
#pragma unroll
      for (int j = 0; j < 4; ++j) acc[i][j] = mfma16(ac[i], b0[j], acc[i][j]);
    __builtin_amdgcn_s_setprio(0);
    if constexpr (EPI == 2) {
#pragma unroll
      for (int i = 0; i < MH; ++i)
#pragma unroll
        for (int e = 0; e < 8; ++e) rs[i] += (float)ac[i][e];
    }
    asm volatile("s_waitcnt vmcnt(6)" ::: "memory");
    __builtin_amdgcn_s_barrier();

    // ---- ph2: MFMA (group0, kc1); prefetch f3 = (group1, kc0) ----
    stageA(nxt, 1, tn1);
    __builtin_amdgcn_s_barrier();
#pragma unroll
    for (int i = 0; i < MH; ++i) ac[i] = ldA(cur, MH + i, 0);
    asm volatile("s_waitcnt lgkmcnt(4)" ::: "memory");
    __builtin_amdgcn_sched_barrier(0);
    __builtin_amdgcn_s_setprio(1);
#pragma unroll
    for (int i = 0; i < MH; ++i)
#pragma unroll
      for (int j = 0; j < 4; ++j) acc[i][j] = mfma16(ad[i], b1[j], acc[i][j]);
    __builtin_amdgcn_s_setprio(0);
    if constexpr (EPI == 2) {
#pragma unroll
      for (int i = 0; i < MH; ++i)
#pragma unroll
        for (int e = 0; e < 8; ++e) rs[i] += (float)ad[i][e];
    }
    __builtin_amdgcn_s_barrier();

    // ---- ph3: MFMA (group1, kc0); prefetch f4 = (group1, kc1) ----
    stageA(cur, 0, tn2);
    __builtin_amdgcn_s_barrier();
#pragma unroll
    for (int i = 0; i < MH; ++i) ad[i] = ldA(cur, MH + i, 1);
    asm volatile("s_waitcnt lgkmcnt(4)" ::: "memory");
    __builtin_amdgcn_sched_barrier(0);
    __builtin_amdgcn_s_setprio(1);
#pragma unroll
    for (int i = 0; i < MH; ++i)
#pragma unroll
      for (int j = 0; j < 4; ++j) acc[MH + i][j] = mfma16(ac[i], b0[j], acc[MH + i][j]);
    __builtin_amdgcn_s_setprio(0);
    if constexpr (EPI == 2) {
#pragma unroll
      for (int i = 0; i < MH; ++i)
#pragma unroll
        for (int e = 0; e < 8; ++e) rs[MH + i] += (float)ac[i][e];
    }
    __builtin_amdgcn_s_barrier();

    // ---- ph4: MFMA (group1, kc1) ----
    stageB(cur, 0, tn2);
    __builtin_amdgcn_s_barrier();
    asm volatile("s_waitcnt lgkmcnt(0)" ::: "memory");
    __builtin_amdgcn_sched_barrier(0);
    __builtin_amdgcn_s_setprio(1);
#pragma unroll
    for (int i = 0; i < MH; ++i)
#pragma unroll
      for (int j = 0; j < 4; ++j) acc[MH + i][j] = mfma16(ad[i], b1[j], acc[MH + i][j]);
    __builtin_amdgcn_s_setprio(0);
    if constexpr (EPI == 2) {
#pragma unroll
      for (int i = 0; i < MH; ++i)
#pragma unroll
        for (int e = 0; e < 8; ++e) rs[MH + i] += (float)ad[i][e];
    }
    asm volatile("s_waitcnt vmcnt(6)" ::: "memory");
    __builtin_amdgcn_s_barrier();
  }

  // ---- EPI==2: finalize rowsums: g-reduce, relay via LDS to C-layout ----
  float* rsL = (float*)&aLds[0][0];
  if constexpr (EPI == 2) {
#pragma unroll
    for (int mi = 0; mi < MF; ++mi) {
      rs[mi] += __shfl_xor(rs[mi], 16);
      rs[mi] += __shfl_xor(rs[mi], 32);
    }
    __syncthreads();
    if (wc == 0) {
#pragma unroll
      for (int mi = 0; mi < MF; ++mi) rsL[wr * 128 + mi * 16 + l15] = rs[mi];
    }
    __syncthreads();
  }

  // epilogue
#pragma unroll
  for (int mi = 0; mi < MF; ++mi) {
    int row = bm + wr * 128 + mi * 16 + g * 4;
#pragma unroll
    for (int j = 0; j < 4; ++j) {
      int col = bn + wc * 64 + j * 16 + l15;
      float bcv = (EPI == 0 && biasCol) ? biasCol[col] : 0.0f;
#pragma unroll
      for (int rr = 0; rr < 4; ++rr) {
        float v;
        if constexpr (EPI == 1) {
          float mval = Mk[(size_t)(row + rr) * 2048 + col];
          v = exp2f(fmaf(acc[mi][j][rr], C1, mval * C2));
        } else if constexpr (EPI == 2) {
          v = acc[mi][j][rr] / rsL[wr * 128 + mi * 16 + g * 4 + rr];
        } else {
          float brv = biasRow ? biasRow[row + rr] : 0.0f;
          v = acc[mi][j][rr] + bcv + brv;
        }
        if constexpr (sizeof(CT) == 2)
          C[(size_t)(row + rr) * ldc + col] = f2bf(v);
        else
          C[(size_t)(row + rr) * ldc + col] = v;
      }
    }
  }
}

extern "C" void kernel_launch(void* const* d_in, const int* in_sizes, int n_in,
                              void* d_out, int out_size, void* d_ws, size_t ws_size,
                              hipStream_t stream) {
  const float* primary = (const float*)d_in[0];
  const float* ctx     = (const float*)d_in[1];
  const float* mask    = (const float*)d_in[2];
  const float* Wq      = (const float*)d_in[3];
  const float* bq      = (const float*)d_in[4];
  const float* Wk      = (const float*)d_in[5];
  const float* bk      = (const float*)d_in[6];
  const float* Wv      = (const float*)d_in[7];
  const float* bv      = (const float*)d_in[8];
  float* out = (float*)d_out;

  char* ws = (char*)d_ws;
  // Layout (peak 90.2 MB):
  //   [0, 16.7M)    qbf
  //   [16.7, 33.5M) kbf
  //   [33.5, 50.3M) vtbf
  //   [50.3, 67M)   prim_bf  } P (unnorm softmax numerator, bf16) overlays
  //   [67, 83.9M)   ctx_bf   } [50.3, 83.9M) after projections are done
  //   [83.9, 90.2M) wqt/wkt/wvt
  u16* qbf     = (u16*)(ws);
  u16* kbf     = (u16*)(ws + 16777216);
  u16* vtbf    = (u16*)(ws + 2 * 16777216);
  u16* prim_bf = (u16*)(ws + 3 * 16777216);
  u16* ctx_bf  = (u16*)(ws + 4 * 16777216);
  u16* wqt     = (u16*)(ws + 5 * 16777216);
  u16* wkt     = (u16*)(ws + 5 * 16777216 + 2097152);
  u16* wvt     = (u16*)(ws + 5 * 16777216 + 2 * 2097152);
  u16* pbf     = (u16*)(ws + 3 * 16777216);  // P overlays prim/ctx

  cvt_f32_bf16<<<2048, 256, 0, stream>>>(primary, prim_bf, 8388608 / 4);
  cvt_f32_bf16<<<2048, 256, 0, stream>>>(ctx, ctx_bf, 8388608 / 4);
  wt_transpose<<<dim3(32, 32, 3), dim3(32, 8), 0, stream>>>(Wq, Wk, Wv, wqt, wkt, wvt);

  // Q = primary @ Wq + bq ; K = ctx @ Wk + bk  (z-batched, 256 blocks)
  gemm256<u16, 0><<<dim3(32, 4, 2), 512, 0, stream>>>(
      prim_bf, wqt, bq, bk, nullptr, nullptr, qbf, 1024, 1024, 1024, 1024,
      8192 * 1024LL, 1024 * 1024LL, 8192 * 1024LL, 0);
  // V^T = Wv^T @ ctx^T + bv (row bias) -> vtbf [1024 x 8192]
  gemm256<u16, 0><<<dim3(4, 32, 1), 512, 0, stream>>>(
      wvt, ctx_bf, nullptr, nullptr, bv, nullptr, vtbf, 1024, 1024, 1024, 8192,
      0, 0, 0, 0);
  // P = exp2(QK^T*C1 + mask*C2) -> pbf [4][2048 x 2048] bf16 (unnormalized)
  gemm256<u16, 1><<<dim3(8, 8, 4), 512, 0, stream>>>(
      qbf, kbf, nullptr, nullptr, nullptr, mask, pbf, 1024, 1024, 1024, 2048,
      2048 * 1024LL, 2048 * 1024LL, 2048 * 2048LL, 2048 * 2048LL);
  // O = (P @ V) / rowsum(P) -> out fp32 [4][2048 x 1024]
  gemm256<float, 2><<<dim3(8, 4, 4), 512, 0, stream>>>(
      pbf, vtbf, nullptr, nullptr, nullptr, nullptr, out, 2048, 2048, 8192, 1024,
      2048 * 2048LL, 2048LL, 2048 * 1024LL, 0);
}

// Round 8
// 268.754 us; speedup vs baseline: 1.1288x; 1.1288x over previous
//
#include <hip/hip_runtime.h>
#include <stdint.h>

typedef unsigned short u16;
typedef __bf16 bf16_t;
typedef bf16_t bf16x8 __attribute__((ext_vector_type(8)));
typedef float f32x4 __attribute__((ext_vector_type(4)));
typedef u16 u16x4 __attribute__((ext_vector_type(4)));
typedef u16 u16x8 __attribute__((ext_vector_type(8)));

__device__ __forceinline__ u16 f2bf(float f) {
  union { float f; uint32_t u; } v;
  v.f = f;
  uint32_t u = v.u + 0x7fffu + ((v.u >> 16) & 1u);
  return (u16)(u >> 16);
}

__device__ __forceinline__ float bf2f(u16 x) {
  union { uint32_t u; float f; } v;
  v.u = ((uint32_t)x) << 16;
  return v.f;
}

__device__ __forceinline__ void gload16(const void* g, void* l) {
  __builtin_amdgcn_global_load_lds(
      (__attribute__((address_space(1))) void*)g,
      (__attribute__((address_space(3))) void*)l, 16, 0, 0);
}

__device__ __forceinline__ f32x4 mfma16(bf16x8 a, bf16x8 b, f32x4 c) {
  return __builtin_amdgcn_mfma_f32_16x16x32_bf16(a, b, c, 0, 0, 0);
}

// ---------------- fp32 -> bf16 convert ----------------
__global__ void cvt_f32_bf16(const float* __restrict__ in, u16* __restrict__ out, int n4) {
  int i = blockIdx.x * blockDim.x + threadIdx.x;
  int stride = gridDim.x * blockDim.x;
  for (; i < n4; i += stride) {
    float4 v = *((const float4*)in + i);
    u16x4 o;
    o.x = f2bf(v.x); o.y = f2bf(v.y); o.z = f2bf(v.z); o.w = f2bf(v.w);
    *((u16x4*)out + i) = o;
  }
}

// ---------------- weight transpose + convert: Wt[n][k] = (bf16)W[k][n] ----------------
__global__ void wt_transpose(const float* __restrict__ Wq, const float* __restrict__ Wk,
                             const float* __restrict__ Wv, u16* __restrict__ Oq,
                             u16* __restrict__ Ok, u16* __restrict__ Ov) {
  const float* W = blockIdx.z == 0 ? Wq : (blockIdx.z == 1 ? Wk : Wv);
  u16* O = blockIdx.z == 0 ? Oq : (blockIdx.z == 1 ? Ok : Ov);
  __shared__ float t[32][33];
  int x = threadIdx.x, y = threadIdx.y;
  int n0 = blockIdx.x * 32, k0 = blockIdx.y * 32;
#pragma unroll
  for (int i = 0; i < 32; i += 8)
    t[y + i][x] = W[(size_t)(k0 + y + i) * 1024 + n0 + x];
  __syncthreads();
#pragma unroll
  for (int i = 0; i < 32; i += 8)
    O[(size_t)(n0 + y + i) * 1024 + k0 + x] = f2bf(t[x][y + i]);
}

// ---------------- 256x256 8-phase bf16 GEMM: C = A[M][K] * Bt[N][K]^T + bias ----------
// 512 threads = 8 waves (2M x 4N). BK=64, double-buffered LDS (128 KiB),
// 4 phases per K-tile: (A-group, kc) quadrants, 16 MFMA each.
// Round-8 change vs round-4: stage issues moved to earliest-legal phase for
// maximum latency-hiding distance (5-6 phases instead of 4-5):
//   ph1: stage A1(t+1)            (nxt group1 free after t-1 ph4)
//   ph3: stage A0,B0,B1(t+2)      (cur group0/B free after t ph2)
// Drains: vmcnt(8) at ph2-end (A1(t) landed, needed ph3) and
//         vmcnt(8) at ph4-end (A0B0B1(t+1) landed, needed t+1 ph1).
// In-flight never below 8 loads (4 units).
template <typename CT>
__global__ __launch_bounds__(512, 2) void gemm256(
    const u16* __restrict__ A, const u16* __restrict__ Bt,
    const float* __restrict__ bc0, const float* __restrict__ bc1,
    const float* __restrict__ biasRow,
    CT* __restrict__ C, int K, int lda, int ldb, int ldc,
    long long bsA, long long bsB, long long bsC) {
  A += (size_t)blockIdx.z * bsA;
  Bt += (size_t)blockIdx.z * bsB;
  C += (size_t)blockIdx.z * bsC;
  const float* biasCol = (blockIdx.z == 1) ? bc1 : bc0;

  __shared__ u16 aLds[2][256 * 64];
  __shared__ u16 bLds[2][256 * 64];
  int tid = threadIdx.x;
  int lane = tid & 63, w = tid >> 6;
  int l15 = lane & 15, g = lane >> 4;
  int wr = w >> 2, wc = w & 3;
  int bm = blockIdx.x * 256, bn = blockIdx.y * 256;
  int NT = K >> 6;

  f32x4 acc[8][4] = {};

  // stage A group h: rows h*64..+63 and h*64+128..+191 (2 loads/thread)
  auto stageA = [&](int buf, int h, int tk) {
    int k0 = tk * 64;
    int r = tid >> 3, cd = (tid & 7) * 8;
    int cs = cd ^ ((r & 7) * 8);
    int row0 = h * 64 + r;
    gload16(A + (size_t)(bm + row0) * lda + k0 + cs, &aLds[buf][row0 * 64 + cd]);
    int row1 = row0 + 128;
    gload16(A + (size_t)(bm + row1) * lda + k0 + cs, &aLds[buf][row1 * 64 + cd]);
  };
  // stage B half x: rows x*128..+127 (2 loads/thread)
  auto stageB = [&](int buf, int x, int tk) {
    int k0 = tk * 64;
#pragma unroll
    for (int l = 0; l < 2; ++l) {
      int u = l * 512 + tid;
      int r = u >> 3, cd = (u & 7) * 8;
      int cs = cd ^ ((r & 7) * 8);
      int row = x * 128 + r;
      gload16(Bt + (size_t)(bn + row) * ldb + k0 + cs, &bLds[buf][row * 64 + cd]);
    }
  };
  auto ldA = [&](int buf, int m, int kc) -> bf16x8 {
    int row = wr * 128 + m * 16 + l15;
    int col = (kc * 32 + g * 8) ^ ((row & 7) * 8);
    return *(const bf16x8*)&aLds[buf][row * 64 + col];
  };
  auto ldB = [&](int buf, int j, int kc) -> bf16x8 {
    int row = wc * 64 + j * 16 + l15;
    int col = (kc * 32 + g * 8) ^ ((row & 7) * 8);
    return *(const bf16x8*)&bLds[buf][row * 64 + col];
  };

  // prologue (14 loads, issue order matters for vmcnt accounting):
  //   A0(0),B0(0),B1(0) [6]  |  A1(0) [2]  |  A0(1),B0(1),B1(1) [6]
  stageA(0, 0, 0);
  stageB(0, 0, 0);
  stageB(0, 1, 0);
  stageA(0, 1, 0);
  int t1c = NT > 1 ? 1 : 0;
  stageA(1, 0, t1c);
  stageB(1, 0, t1c);
  stageB(1, 1, t1c);
  // drain A0B0B1(0) (oldest 6), keep 8 in flight, rendezvous
  asm volatile("s_waitcnt vmcnt(8)" ::: "memory");
  __builtin_amdgcn_s_barrier();

  for (int t = 0; t < NT; ++t) {
    int cur = t & 1, nxt = cur ^ 1;
    int tn1 = (t + 1 < NT) ? t + 1 : NT - 1;
    int tn2 = (t + 2 < NT) ? t + 2 : NT - 1;
    bf16x8 ac[4], ad[4], b0[4], b1[4];

    // ---- ph1: MFMA (group0, kc0); stage A1(t+1) ----
#pragma unroll
    for (int i = 0; i < 4; ++i) ac[i] = ldA(cur, i, 0);
#pragma unroll
    for (int j = 0; j < 4; ++j) b0[j] = ldB(cur, j, 0);
    stageA(nxt, 1, tn1);
    __builtin_amdgcn_s_barrier();
    asm volatile("s_waitcnt lgkmcnt(0)" ::: "memory");
    __builtin_amdgcn_sched_barrier(0);
    __builtin_amdgcn_s_setprio(1);
#pragma unroll
    for (int i = 0; i < 4; ++i)
#pragma unroll
      for (int j = 0; j < 4; ++j) acc[i][j] = mfma16(ac[i], b0[j], acc[i][j]);
    __builtin_amdgcn_s_setprio(0);
    __builtin_amdgcn_s_barrier();

    // ---- ph2: MFMA (group0, kc1) ----
#pragma unroll
    for (int i = 0; i < 4; ++i) ad[i] = ldA(cur, i, 1);
#pragma unroll
    for (int j = 0; j < 4; ++j) b1[j] = ldB(cur, j, 1);
    __builtin_amdgcn_s_barrier();
    asm volatile("s_waitcnt lgkmcnt(0)" ::: "memory");
    __builtin_amdgcn_sched_barrier(0);
    __builtin_amdgcn_s_setprio(1);
#pragma unroll
    for (int i = 0; i < 4; ++i)
#pragma unroll
      for (int j = 0; j < 4; ++j) acc[i][j] = mfma16(ad[i], b1[j], acc[i][j]);
    __builtin_amdgcn_s_setprio(0);
    // drain A1(t) (issued t-1 ph1, needed by ph3 reads after this barrier)
    asm volatile("s_waitcnt vmcnt(8)" ::: "memory");
    __builtin_amdgcn_s_barrier();

    // ---- ph3: MFMA (group1, kc0); stage A0,B0,B1(t+2) ----
#pragma unroll
    for (int i = 0; i < 4; ++i) ac[i] = ldA(cur, 4 + i, 0);
    stageA(cur, 0, tn2);
    stageB(cur, 0, tn2);
    stageB(cur, 1, tn2);
    __builtin_amdgcn_s_barrier();
    asm volatile("s_waitcnt lgkmcnt(0)" ::: "memory");
    __builtin_amdgcn_sched_barrier(0);
    __builtin_amdgcn_s_setprio(1);
#pragma unroll
    for (int i = 0; i < 4; ++i)
#pragma unroll
      for (int j = 0; j < 4; ++j) acc[4 + i][j] = mfma16(ac[i], b0[j], acc[4 + i][j]);
    __builtin_amdgcn_s_setprio(0);
    __builtin_amdgcn_s_barrier();

    // ---- ph4: MFMA (group1, kc1) ----
#pragma unroll
    for (int i = 0; i < 4; ++i) ad[i] = ldA(cur, 4 + i, 1);
    __builtin_amdgcn_s_barrier();
    asm volatile("s_waitcnt lgkmcnt(0)" ::: "memory");
    __builtin_amdgcn_sched_barrier(0);
    __builtin_amdgcn_s_setprio(1);
#pragma unroll
    for (int i = 0; i < 4; ++i)
#pragma unroll
      for (int j = 0; j < 4; ++j) acc[4 + i][j] = mfma16(ad[i], b1[j], acc[4 + i][j]);
    __builtin_amdgcn_s_setprio(0);
    // drain A0B0B1(t+1) (issued t-1 ph3, needed by t+1 ph1 after this barrier)
    asm volatile("s_waitcnt vmcnt(8)" ::: "memory");
    __builtin_amdgcn_s_barrier();
  }

  // epilogue
#pragma unroll
  for (int mi = 0; mi < 8; ++mi) {
    int row = bm + wr * 128 + mi * 16 + g * 4;
#pragma unroll
    for (int j = 0; j < 4; ++j) {
      int col = bn + wc * 64 + j * 16 + l15;
      float bcv = biasCol ? biasCol[col] : 0.0f;
#pragma unroll
      for (int rr = 0; rr < 4; ++rr) {
        float brv = biasRow ? biasRow[row + rr] : 0.0f;
        float v = acc[mi][j][rr] + bcv + brv;
        if constexpr (sizeof(CT) == 2)
          C[(size_t)(row + rr) * ldc + col] = f2bf(v);
        else
          C[(size_t)(row + rr) * ldc + col] = v;
      }
    }
  }
}

// ---------------- fused mask + row softmax ----------------
__global__ __launch_bounds__(256) void softmax_mask(
    const u16* __restrict__ S, const float* __restrict__ mask, u16* __restrict__ P) {
  const float C1 = 0.04508422f;    // log2(e)/32
  const float C2 = -1.4426950e9f;  // -1e9*log2(e)
  int wid = (blockIdx.x * blockDim.x + threadIdx.x) >> 6;  // global wave = row
  int lane = threadIdx.x & 63;
  size_t base = (size_t)wid * 2048;
  const u16* sp = S + base;
  const float* mp = mask + base;

  float a[32];
#pragma unroll
  for (int pass = 0; pass < 4; ++pass) {
    int e0 = pass * 512 + lane * 8;
    u16x8 sv = *(const u16x8*)(sp + e0);
    float4 m0 = *(const float4*)(mp + e0);
    float4 m1 = *(const float4*)(mp + e0 + 4);
    a[pass * 8 + 0] = bf2f(sv[0]) * C1 + m0.x * C2;
    a[pass * 8 + 1] = bf2f(sv[1]) * C1 + m0.y * C2;
    a[pass * 8 + 2] = bf2f(sv[2]) * C1 + m0.z * C2;
    a[pass * 8 + 3] = bf2f(sv[3]) * C1 + m0.w * C2;
    a[pass * 8 + 4] = bf2f(sv[4]) * C1 + m1.x * C2;
    a[pass * 8 + 5] = bf2f(sv[5]) * C1 + m1.y * C2;
    a[pass * 8 + 6] = bf2f(sv[6]) * C1 + m1.z * C2;
    a[pass * 8 + 7] = bf2f(sv[7]) * C1 + m1.w * C2;
  }
  float m = a[0];
#pragma unroll
  for (int i = 1; i < 32; ++i) m = fmaxf(m, a[i]);
#pragma unroll
  for (int off = 32; off >= 1; off >>= 1) m = fmaxf(m, __shfl_xor(m, off));

  float s = 0.0f;
#pragma unroll
  for (int i = 0; i < 32; ++i) {
    a[i] = exp2f(a[i] - m);
    s += a[i];
  }
#pragma unroll
  for (int off = 32; off >= 1; off >>= 1) s += __shfl_xor(s, off);
  float inv = 1.0f / s;

  u16* pp = P + base;
#pragma unroll
  for (int pass = 0; pass < 4; ++pass) {
    int e0 = pass * 512 + lane * 8;
    u16x8 o;
#pragma unroll
    for (int j = 0; j < 8; ++j) o[j] = f2bf(a[pass * 8 + j] * inv);
    *(u16x8*)(pp + e0) = o;
  }
}

extern "C" void kernel_launch(void* const* d_in, const int* in_sizes, int n_in,
                              void* d_out, int out_size, void* d_ws, size_t ws_size,
                              hipStream_t stream) {
  const float* primary = (const float*)d_in[0];
  const float* ctx     = (const float*)d_in[1];
  const float* mask    = (const float*)d_in[2];
  const float* Wq      = (const float*)d_in[3];
  const float* bq      = (const float*)d_in[4];
  const float* Wk      = (const float*)d_in[5];
  const float* bk      = (const float*)d_in[6];
  const float* Wv      = (const float*)d_in[7];
  const float* bv      = (const float*)d_in[8];
  float* out = (float*)d_out;

  char* ws = (char*)d_ws;
  // Layout (peak 90.2 MB):
  //   [0, 16.7M)    qbf      } P overlays [0, 33.5M)
  //   [16.7, 33.5M) kbf      }
  //   [33.5, 50.3M) vtbf
  //   [50.3, 67M)   prim_bf  } S bf16 overlays [50.3, 83.9M)
  //   [67, 83.9M)   ctx_bf   }
  //   [83.9, 90.2M) wqt/wkt/wvt
  u16* qbf     = (u16*)(ws);
  u16* kbf     = (u16*)(ws + 16777216);
  u16* vtbf    = (u16*)(ws + 2 * 16777216);
  u16* prim_bf = (u16*)(ws + 3 * 16777216);
  u16* ctx_bf  = (u16*)(ws + 4 * 16777216);
  u16* wqt     = (u16*)(ws + 5 * 16777216);
  u16* wkt     = (u16*)(ws + 5 * 16777216 + 2097152);
  u16* wvt     = (u16*)(ws + 5 * 16777216 + 2 * 2097152);
  u16* sbf     = (u16*)(ws + 3 * 16777216);
  u16* pbf     = (u16*)(ws);

  cvt_f32_bf16<<<2048, 256, 0, stream>>>(primary, prim_bf, 8388608 / 4);
  cvt_f32_bf16<<<2048, 256, 0, stream>>>(ctx, ctx_bf, 8388608 / 4);
  wt_transpose<<<dim3(32, 32, 3), dim3(32, 8), 0, stream>>>(Wq, Wk, Wv, wqt, wkt, wvt);

  // Q = primary @ Wq + bq ; K = ctx @ Wk + bk  (z-batched, 256 blocks)
  gemm256<u16><<<dim3(32, 4, 2), 512, 0, stream>>>(
      prim_bf, wqt, bq, bk, nullptr, qbf, 1024, 1024, 1024, 1024,
      8192 * 1024LL, 1024 * 1024LL, 8192 * 1024LL);
  // V^T = Wv^T @ ctx^T + bv (row bias) -> vtbf [1024 x 8192]
  gemm256<u16><<<dim3(4, 32, 1), 512, 0, stream>>>(
      wvt, ctx_bf, nullptr, nullptr, bv, vtbf, 1024, 1024, 1024, 8192, 0, 0, 0);
  // S = Q @ K^T -> sbf [4][2048 x 2048] bf16
  gemm256<u16><<<dim3(8, 8, 4), 512, 0, stream>>>(
      qbf, kbf, nullptr, nullptr, nullptr, sbf, 1024, 1024, 1024, 2048,
      2048 * 1024LL, 2048 * 1024LL, 2048 * 2048LL);
  // P = softmax(S*C1 + mask*C2) -> pbf
  softmax_mask<<<2048, 256, 0, stream>>>(sbf, mask, pbf);
  // O = P @ (V^T)^T -> out fp32 [4][2048 x 1024]
  gemm256<float><<<dim3(8, 4, 4), 512, 0, stream>>>(
      pbf, vtbf, nullptr, nullptr, nullptr, out, 2048, 2048, 8192, 1024,
      2048 * 2048LL, 2048LL, 2048 * 1024LL);
}

// Round 9
// 262.199 us; speedup vs baseline: 1.1570x; 1.0250x over previous
//
#include <hip/hip_runtime.h>
#include <stdint.h>

typedef unsigned short u16;
typedef __bf16 bf16_t;
typedef bf16_t bf16x8 __attribute__((ext_vector_type(8)));
typedef float f32x4 __attribute__((ext_vector_type(4)));
typedef u16 u16x4 __attribute__((ext_vector_type(4)));
typedef u16 u16x8 __attribute__((ext_vector_type(8)));

__device__ __forceinline__ u16 f2bf(float f) {
  union { float f; uint32_t u; } v;
  v.f = f;
  uint32_t u = v.u + 0x7fffu + ((v.u >> 16) & 1u);
  return (u16)(u >> 16);
}

__device__ __forceinline__ float bf2f(u16 x) {
  union { uint32_t u; float f; } v;
  v.u = ((uint32_t)x) << 16;
  return v.f;
}

__device__ __forceinline__ void gload16(const void* g, void* l) {
  __builtin_amdgcn_global_load_lds(
      (__attribute__((address_space(1))) void*)g,
      (__attribute__((address_space(3))) void*)l, 16, 0, 0);
}

__device__ __forceinline__ f32x4 mfma16(bf16x8 a, bf16x8 b, f32x4 c) {
  return __builtin_amdgcn_mfma_f32_16x16x32_bf16(a, b, c, 0, 0, 0);
}

// ---------------- fp32 -> bf16 convert (two tensors in one dispatch) ----------------
__global__ void cvt2_f32_bf16(const float* __restrict__ in0, u16* __restrict__ out0,
                              const float* __restrict__ in1, u16* __restrict__ out1,
                              int n4each) {
  int half = gridDim.x >> 1;
  const float* in = (blockIdx.x < half) ? in0 : in1;
  u16* out = (blockIdx.x < half) ? out0 : out1;
  int b = (blockIdx.x < half) ? blockIdx.x : blockIdx.x - half;
  int i = b * blockDim.x + threadIdx.x;
  int stride = half * blockDim.x;
  for (; i < n4each; i += stride) {
    float4 v = *((const float4*)in + i);
    u16x4 o;
    o.x = f2bf(v.x); o.y = f2bf(v.y); o.z = f2bf(v.z); o.w = f2bf(v.w);
    *((u16x4*)out + i) = o;
  }
}

// ---------------- weight transpose + convert: Wt[n][k] = (bf16)W[k][n] ----------------
__global__ void wt_transpose(const float* __restrict__ Wq, const float* __restrict__ Wk,
                             const float* __restrict__ Wv, u16* __restrict__ Oq,
                             u16* __restrict__ Ok, u16* __restrict__ Ov) {
  const float* W = blockIdx.z == 0 ? Wq : (blockIdx.z == 1 ? Wk : Wv);
  u16* O = blockIdx.z == 0 ? Oq : (blockIdx.z == 1 ? Ok : Ov);
  __shared__ float t[32][33];
  int x = threadIdx.x, y = threadIdx.y;
  int n0 = blockIdx.x * 32, k0 = blockIdx.y * 32;
#pragma unroll
  for (int i = 0; i < 32; i += 8)
    t[y + i][x] = W[(size_t)(k0 + y + i) * 1024 + n0 + x];
  __syncthreads();
#pragma unroll
  for (int i = 0; i < 32; i += 8)
    O[(size_t)(n0 + y + i) * 1024 + k0 + x] = f2bf(t[x][y + i]);
}

// ---------------- 256x256 8-phase bf16 GEMM: C = A[M][K] * Bt[N][K]^T + bias ----------
// 512 threads = 8 waves (2M x 4N). BK=64, double-buffered LDS (128 KiB).
// VERBATIM round-4 schedule (proven best: 63 us/dispatch, 240.6 total).
// swz==1 (S-GEMM grid (8,8,4) only): bijective block remap giving XCD pair
// {2z,2z+1} ownership of batch z; each XCD one by-half x all bx. Per-XCD
// concurrent L2 footprint 18.7 MB -> 6 MB (A 8 panels + B 4 panels).
template <typename CT>
__global__ __launch_bounds__(512, 2) void gemm256(
    const u16* __restrict__ A, const u16* __restrict__ Bt,
    const float* __restrict__ bc0, const float* __restrict__ bc1,
    const float* __restrict__ biasRow,
    CT* __restrict__ C, int K, int lda, int ldb, int ldc,
    long long bsA, long long bsB, long long bsC, int swz) {
  int bx = blockIdx.x, by = blockIdx.y, bz = blockIdx.z;
  if (swz == 1) {
    // grid (8,8,4): lin = bx + 8*by + 64*bz; XCD = lin & 7 (round-robin).
    int lin = blockIdx.x + 8 * (blockIdx.y + 8 * blockIdx.z);
    int j = lin & 7, r = lin >> 3;          // j = XCD, r in [0,32)
    bz = j >> 1;                            // XCD pair owns batch z
    bx = r & 7;                             // all bx on each XCD
    by = ((j & 1) << 2) | (r >> 3);         // by-half per XCD
  }
  A += (size_t)bz * bsA;
  Bt += (size_t)bz * bsB;
  C += (size_t)bz * bsC;
  const float* biasCol = (bz == 1) ? bc1 : bc0;

  __shared__ u16 aLds[2][256 * 64];
  __shared__ u16 bLds[2][256 * 64];
  int tid = threadIdx.x;
  int lane = tid & 63, w = tid >> 6;
  int l15 = lane & 15, g = lane >> 4;
  int wr = w >> 2, wc = w & 3;
  int bm = bx * 256, bn = by * 256;
  int NT = K >> 6;

  f32x4 acc[8][4] = {};

  auto stageA = [&](int buf, int h, int tk) {
    int k0 = tk * 64;
    int r = tid >> 3, cd = (tid & 7) * 8;
    int cs = cd ^ ((r & 7) * 8);
    int row0 = h * 64 + r;
    gload16(A + (size_t)(bm + row0) * lda + k0 + cs, &aLds[buf][row0 * 64 + cd]);
    int row1 = row0 + 128;
    gload16(A + (size_t)(bm + row1) * lda + k0 + cs, &aLds[buf][row1 * 64 + cd]);
  };
  auto stageB = [&](int buf, int x, int tk) {
    int k0 = tk * 64;
#pragma unroll
    for (int l = 0; l < 2; ++l) {
      int u = l * 512 + tid;
      int r = u >> 3, cd = (u & 7) * 8;
      int cs = cd ^ ((r & 7) * 8);
      int row = x * 128 + r;
      gload16(Bt + (size_t)(bn + row) * ldb + k0 + cs, &bLds[buf][row * 64 + cd]);
    }
  };
  auto ldA = [&](int buf, int m, int kc) -> bf16x8 {
    int row = wr * 128 + m * 16 + l15;
    int col = (kc * 32 + g * 8) ^ ((row & 7) * 8);
    return *(const bf16x8*)&aLds[buf][row * 64 + col];
  };
  auto ldB = [&](int buf, int j, int kc) -> bf16x8 {
    int row = wc * 64 + j * 16 + l15;
    int col = (kc * 32 + g * 8) ^ ((row & 7) * 8);
    return *(const bf16x8*)&bLds[buf][row * 64 + col];
  };

  // prologue: 6 units in issue order A0(0),B0(0),B1(0),A1(0),A0(1),B0(1)
  stageA(0, 0, 0);
  stageB(0, 0, 0);
  stageB(0, 1, 0);
  stageA(0, 1, 0);
  int t1c = NT > 1 ? 1 : 0;
  stageA(1, 0, t1c);
  stageB(1, 0, t1c);
  asm volatile("s_waitcnt vmcnt(6)" ::: "memory");
  __builtin_amdgcn_s_barrier();

  for (int t = 0; t < NT; ++t) {
    int cur = t & 1, nxt = cur ^ 1;
    int tn1 = (t + 1 < NT) ? t + 1 : NT - 1;
    int tn2 = (t + 2 < NT) ? t + 2 : NT - 1;
    bf16x8 a0[4], b0[4], b1[4];

    // ---- ph1: (Mhalf0, kc0) ----
#pragma unroll
    for (int i = 0; i < 4; ++i) a0[i] = ldA(cur, i, 0);
#pragma unroll
    for (int j = 0; j < 4; ++j) b0[j] = ldB(cur, j, 0);
    stageB(nxt, 1, tn1);
    __builtin_amdgcn_s_barrier();
    asm volatile("s_waitcnt lgkmcnt(0)" ::: "memory");
    __builtin_amdgcn_sched_barrier(0);
    __builtin_amdgcn_s_setprio(1);
#pragma unroll
    for (int i = 0; i < 4; ++i)
#pragma unroll
      for (int j = 0; j < 4; ++j) acc[i][j] = mfma16(a0[i], b0[j], acc[i][j]);
    __builtin_amdgcn_s_setprio(0);
    __builtin_amdgcn_s_barrier();

    // ---- ph2: (Mhalf0, kc1) ----
#pragma unroll
    for (int i = 0; i < 4; ++i) a0[i] = ldA(cur, i, 1);
#pragma unroll
    for (int j = 0; j < 4; ++j) b1[j] = ldB(cur, j, 1);
    stageA(nxt, 1, tn1);
    __builtin_amdgcn_s_barrier();
    asm volatile("s_waitcnt lgkmcnt(0)" ::: "memory");
    __builtin_amdgcn_sched_barrier(0);
    __builtin_amdgcn_s_setprio(1);
#pragma unroll
    for (int i = 0; i < 4; ++i)
#pragma unroll
      for (int j = 0; j < 4; ++j) acc[i][j] = mfma16(a0[i], b1[j], acc[i][j]);
    __builtin_amdgcn_s_setprio(0);
    // drain A1(t) (consumed next phase by all waves) BEFORE the barrier
    asm volatile("s_waitcnt vmcnt(8)" ::: "memory");
    __builtin_amdgcn_s_barrier();

    // ---- ph3: (Mhalf1, kc0) ----
#pragma unroll
    for (int i = 0; i < 4; ++i) a0[i] = ldA(cur, 4 + i, 0);
    stageA(cur, 0, tn2);
    __builtin_amdgcn_s_barrier();
    asm volatile("s_waitcnt lgkmcnt(0)" ::: "memory");
    __builtin_amdgcn_sched_barrier(0);
    __builtin_amdgcn_s_setprio(1);
#pragma unroll
    for (int i = 0; i < 4; ++i)
#pragma unroll
      for (int j = 0; j < 4; ++j) acc[4 + i][j] = mfma16(a0[i], b0[j], acc[4 + i][j]);
    __builtin_amdgcn_s_setprio(0);
    __builtin_amdgcn_s_barrier();

    // ---- ph4: (Mhalf1, kc1) ----
#pragma unroll
    for (int i = 0; i < 4; ++i) a0[i] = ldA(cur, 4 + i, 1);
    stageB(cur, 0, tn2);
    __builtin_amdgcn_s_barrier();
    asm volatile("s_waitcnt lgkmcnt(0)" ::: "memory");
    __builtin_amdgcn_sched_barrier(0);
    __builtin_amdgcn_s_setprio(1);
#pragma unroll
    for (int i = 0; i < 4; ++i)
#pragma unroll
      for (int j = 0; j < 4; ++j) acc[4 + i][j] = mfma16(a0[i], b1[j], acc[4 + i][j]);
    __builtin_amdgcn_s_setprio(0);
    // drain A0(t+1),B0(t+1),B1(t+1) (consumed at t+1 ph1) BEFORE the barrier
    asm volatile("s_waitcnt vmcnt(6)" ::: "memory");
    __builtin_amdgcn_s_barrier();
  }

  // epilogue
#pragma unroll
  for (int mi = 0; mi < 8; ++mi) {
    int row = bm + wr * 128 + mi * 16 + g * 4;
#pragma unroll
    for (int j = 0; j < 4; ++j) {
      int col = bn + wc * 64 + j * 16 + l15;
      float bcv = biasCol ? biasCol[col] : 0.0f;
#pragma unroll
      for (int rr = 0; rr < 4; ++rr) {
        float brv = biasRow ? biasRow[row + rr] : 0.0f;
        float v = acc[mi][j][rr] + bcv + brv;
        if constexpr (sizeof(CT) == 2)
          C[(size_t)(row + rr) * ldc + col] = f2bf(v);
        else
          C[(size_t)(row + rr) * ldc + col] = v;
      }
    }
  }
}

// ---------------- fused mask + row softmax ----------------
__global__ __launch_bounds__(256) void softmax_mask(
    const u16* __restrict__ S, const float* __restrict__ mask, u16* __restrict__ P) {
  const float C1 = 0.04508422f;    // log2(e)/32
  const float C2 = -1.4426950e9f;  // -1e9*log2(e)
  int wid = (blockIdx.x * blockDim.x + threadIdx.x) >> 6;  // global wave = row
  int lane = threadIdx.x & 63;
  size_t base = (size_t)wid * 2048;
  const u16* sp = S + base;
  const float* mp = mask + base;

  float a[32];
#pragma unroll
  for (int pass = 0; pass < 4; ++pass) {
    int e0 = pass * 512 + lane * 8;
    u16x8 sv = *(const u16x8*)(sp + e0);
    float4 m0 = *(const float4*)(mp + e0);
    float4 m1 = *(const float4*)(mp + e0 + 4);
    a[pass * 8 + 0] = bf2f(sv[0]) * C1 + m0.x * C2;
    a[pass * 8 + 1] = bf2f(sv[1]) * C1 + m0.y * C2;
    a[pass * 8 + 2] = bf2f(sv[2]) * C1 + m0.z * C2;
    a[pass * 8 + 3] = bf2f(sv[3]) * C1 + m0.w * C2;
    a[pass * 8 + 4] = bf2f(sv[4]) * C1 + m1.x * C2;
    a[pass * 8 + 5] = bf2f(sv[5]) * C1 + m1.y * C2;
    a[pass * 8 + 6] = bf2f(sv[6]) * C1 + m1.z * C2;
    a[pass * 8 + 7] = bf2f(sv[7]) * C1 + m1.w * C2;
  }
  float m = a[0];
#pragma unroll
  for (int i = 1; i < 32; ++i) m = fmaxf(m, a[i]);
#pragma unroll
  for (int off = 32; off >= 1; off >>= 1) m = fmaxf(m, __shfl_xor(m, off));

  float s = 0.0f;
#pragma unroll
  for (int i = 0; i < 32; ++i) {
    a[i] = exp2f(a[i] - m);
    s += a[i];
  }
#pragma unroll
  for (int off = 32; off >= 1; off >>= 1) s += __shfl_xor(s, off);
  float inv = 1.0f / s;

  u16* pp = P + base;
#pragma unroll
  for (int pass = 0; pass < 4; ++pass) {
    int e0 = pass * 512 + lane * 8;
    u16x8 o;
#pragma unroll
    for (int j = 0; j < 8; ++j) o[j] = f2bf(a[pass * 8 + j] * inv);
    *(u16x8*)(pp + e0) = o;
  }
}

extern "C" void kernel_launch(void* const* d_in, const int* in_sizes, int n_in,
                              void* d_out, int out_size, void* d_ws, size_t ws_size,
                              hipStream_t stream) {
  const float* primary = (const float*)d_in[0];
  const float* ctx     = (const float*)d_in[1];
  const float* mask    = (const float*)d_in[2];
  const float* Wq      = (const float*)d_in[3];
  const float* bq      = (const float*)d_in[4];
  const float* Wk      = (const float*)d_in[5];
  const float* bk      = (const float*)d_in[6];
  const float* Wv      = (const float*)d_in[7];
  const float* bv      = (const float*)d_in[8];
  float* out = (float*)d_out;

  char* ws = (char*)d_ws;
  // Layout (peak 90.2 MB):
  //   [0, 16.7M)    qbf      } P overlays [0, 33.5M)
  //   [16.7, 33.5M) kbf      }
  //   [33.5, 50.3M) vtbf
  //   [50.3, 67M)   prim_bf  } S bf16 overlays [50.3, 83.9M)
  //   [67, 83.9M)   ctx_bf   }
  //   [83.9, 90.2M) wqt/wkt/wvt
  u16* qbf     = (u16*)(ws);
  u16* kbf     = (u16*)(ws + 16777216);
  u16* vtbf    = (u16*)(ws + 2 * 16777216);
  u16* prim_bf = (u16*)(ws + 3 * 16777216);
  u16* ctx_bf  = (u16*)(ws + 4 * 16777216);
  u16* wqt     = (u16*)(ws + 5 * 16777216);
  u16* wkt     = (u16*)(ws + 5 * 16777216 + 2097152);
  u16* wvt     = (u16*)(ws + 5 * 16777216 + 2 * 2097152);
  u16* sbf     = (u16*)(ws + 3 * 16777216);
  u16* pbf     = (u16*)(ws);

  cvt2_f32_bf16<<<2048, 256, 0, stream>>>(primary, prim_bf, ctx, ctx_bf, 8388608 / 4);
  wt_transpose<<<dim3(32, 32, 3), dim3(32, 8), 0, stream>>>(Wq, Wk, Wv, wqt, wkt, wvt);

  // Q = primary @ Wq + bq ; K = ctx @ Wk + bk  (z-batched, 256 blocks)
  gemm256<u16><<<dim3(32, 4, 2), 512, 0, stream>>>(
      prim_bf, wqt, bq, bk, nullptr, qbf, 1024, 1024, 1024, 1024,
      8192 * 1024LL, 1024 * 1024LL, 8192 * 1024LL, 0);
  // V^T = Wv^T @ ctx^T + bv (row bias) -> vtbf [1024 x 8192]
  gemm256<u16><<<dim3(4, 32, 1), 512, 0, stream>>>(
      wvt, ctx_bf, nullptr, nullptr, bv, vtbf, 1024, 1024, 1024, 8192, 0, 0, 0, 0);
  // S = Q @ K^T -> sbf [4][2048 x 2048] bf16  (XCD-footprint swizzle ON)
  gemm256<u16><<<dim3(8, 8, 4), 512, 0, stream>>>(
      qbf, kbf, nullptr, nullptr, nullptr, sbf, 1024, 1024, 1024, 2048,
      2048 * 1024LL, 2048 * 1024LL, 2048 * 2048LL, 1);
  // P = softmax(S*C1 + mask*C2) -> pbf
  softmax_mask<<<2048, 256, 0, stream>>>(sbf, mask, pbf);
  // O = P @ (V^T)^T -> out fp32 [4][2048 x 1024]
  gemm256<float><<<dim3(8, 4, 4), 512, 0, stream>>>(
      pbf, vtbf, nullptr, nullptr, nullptr, out, 2048, 2048, 8192, 1024,
      2048 * 2048LL, 2048LL, 2048 * 1024LL, 0);
}

// Round 10
// 235.388 us; speedup vs baseline: 1.2888x; 1.1139x over previous
//
#include <hip/hip_runtime.h>
#include <stdint.h>

typedef unsigned short u16;
typedef __bf16 bf16_t;
typedef bf16_t bf16x8 __attribute__((ext_vector_type(8)));
typedef float f32x4 __attribute__((ext_vector_type(4)));
typedef u16 u16x4 __attribute__((ext_vector_type(4)));
typedef u16 u16x8 __attribute__((ext_vector_type(8)));

__device__ __forceinline__ u16 f2bf(float f) {
  union { float f; uint32_t u; } v;
  v.f = f;
  uint32_t u = v.u + 0x7fffu + ((v.u >> 16) & 1u);
  return (u16)(u >> 16);
}

__device__ __forceinline__ float bf2f(u16 x) {
  union { uint32_t u; float f; } v;
  v.u = ((uint32_t)x) << 16;
  return v.f;
}

__device__ __forceinline__ void gload16(const void* g, void* l) {
  __builtin_amdgcn_global_load_lds(
      (__attribute__((address_space(1))) void*)g,
      (__attribute__((address_space(3))) void*)l, 16, 0, 0);
}

__device__ __forceinline__ f32x4 mfma16(bf16x8 a, bf16x8 b, f32x4 c) {
  return __builtin_amdgcn_mfma_f32_16x16x32_bf16(a, b, c, 0, 0, 0);
}

// ---------- merged fp32->bf16 convert (prim, ctx) + weight transpose ----------
// grid.x = 2048 (cvt: 1024 prim + 1024 ctx) + 3072 (transpose: 3 x 32 x 32 tiles)
__global__ __launch_bounds__(256) void cvt_wt(
    const float* __restrict__ prim, u16* __restrict__ prim_bf,
    const float* __restrict__ ctx, u16* __restrict__ ctx_bf,
    const float* __restrict__ Wq, const float* __restrict__ Wk,
    const float* __restrict__ Wv, u16* __restrict__ Oq,
    u16* __restrict__ Ok, u16* __restrict__ Ov) {
  int b = blockIdx.x;
  if (b < 2048) {
    const float* in = (b < 1024) ? prim : ctx;
    u16* out = (b < 1024) ? prim_bf : ctx_bf;
    int bb = b & 1023;
    int i = bb * 256 + threadIdx.x;
    const int n4 = 2097152;                 // 8.4M floats / 4
    for (; i < n4; i += 1024 * 256) {
      float4 v = *((const float4*)in + i);
      u16x4 o;
      o.x = f2bf(v.x); o.y = f2bf(v.y); o.z = f2bf(v.z); o.w = f2bf(v.w);
      *((u16x4*)out + i) = o;
    }
  } else {
    int tb = b - 2048;
    int zi = tb >> 10, rem = tb & 1023;
    const float* W = zi == 0 ? Wq : (zi == 1 ? Wk : Wv);
    u16* O = zi == 0 ? Oq : (zi == 1 ? Ok : Ov);
    __shared__ float t[32][33];
    int x = threadIdx.x & 31, y = threadIdx.x >> 5;   // x<32, y<8
    int n0 = (rem & 31) * 32, k0 = (rem >> 5) * 32;
#pragma unroll
    for (int i = 0; i < 32; i += 8)
      t[y + i][x] = W[(size_t)(k0 + y + i) * 1024 + n0 + x];
    __syncthreads();
#pragma unroll
    for (int i = 0; i < 32; i += 8)
      O[(size_t)(n0 + y + i) * 1024 + k0 + x] = f2bf(t[x][y + i]);
  }
}

// ---------------- 256x256 8-phase bf16 GEMM body (round-4 schedule, proven) ----------
// 512 threads = 8 waves (2M x 4N). BK=64, double-buffered LDS (128 KiB).
// Counted vmcnt before the trailing barriers of ph2 (8) / ph4 (6); never 0 in-loop.
template <typename CT>
__device__ __forceinline__ void gemm_body(
    const u16* __restrict__ A, const u16* __restrict__ Bt,
    const float* __restrict__ biasCol, const float* __restrict__ biasRow,
    CT* __restrict__ C, int bm, int bn, int K, int lda, int ldb, int ldc) {
  __shared__ u16 aLds[2][256 * 64];
  __shared__ u16 bLds[2][256 * 64];
  int tid = threadIdx.x;
  int lane = tid & 63, w = tid >> 6;
  int l15 = lane & 15, g = lane >> 4;
  int wr = w >> 2, wc = w & 3;
  int NT = K >> 6;

  f32x4 acc[8][4] = {};

  auto stageA = [&](int buf, int h, int tk) {
    int k0 = tk * 64;
    int r = tid >> 3, cd = (tid & 7) * 8;
    int cs = cd ^ ((r & 7) * 8);
    int row0 = h * 64 + r;
    gload16(A + (size_t)(bm + row0) * lda + k0 + cs, &aLds[buf][row0 * 64 + cd]);
    int row1 = row0 + 128;
    gload16(A + (size_t)(bm + row1) * lda + k0 + cs, &aLds[buf][row1 * 64 + cd]);
  };
  auto stageB = [&](int buf, int x, int tk) {
    int k0 = tk * 64;
#pragma unroll
    for (int l = 0; l < 2; ++l) {
      int u = l * 512 + tid;
      int r = u >> 3, cd = (u & 7) * 8;
      int cs = cd ^ ((r & 7) * 8);
      int row = x * 128 + r;
      gload16(Bt + (size_t)(bn + row) * ldb + k0 + cs, &bLds[buf][row * 64 + cd]);
    }
  };
  auto ldA = [&](int buf, int m, int kc) -> bf16x8 {
    int row = wr * 128 + m * 16 + l15;
    int col = (kc * 32 + g * 8) ^ ((row & 7) * 8);
    return *(const bf16x8*)&aLds[buf][row * 64 + col];
  };
  auto ldB = [&](int buf, int j, int kc) -> bf16x8 {
    int row = wc * 64 + j * 16 + l15;
    int col = (kc * 32 + g * 8) ^ ((row & 7) * 8);
    return *(const bf16x8*)&bLds[buf][row * 64 + col];
  };

  // prologue: 6 units in issue order A0(0),B0(0),B1(0),A1(0),A0(1),B0(1)
  stageA(0, 0, 0);
  stageB(0, 0, 0);
  stageB(0, 1, 0);
  stageA(0, 1, 0);
  int t1c = NT > 1 ? 1 : 0;
  stageA(1, 0, t1c);
  stageB(1, 0, t1c);
  asm volatile("s_waitcnt vmcnt(6)" ::: "memory");
  __builtin_amdgcn_s_barrier();

  for (int t = 0; t < NT; ++t) {
    int cur = t & 1, nxt = cur ^ 1;
    int tn1 = (t + 1 < NT) ? t + 1 : NT - 1;
    int tn2 = (t + 2 < NT) ? t + 2 : NT - 1;
    bf16x8 a0[4], b0[4], b1[4];

    // ---- ph1: (Mhalf0, kc0) ----
#pragma unroll
    for (int i = 0; i < 4; ++i) a0[i] = ldA(cur, i, 0);
#pragma unroll
    for (int j = 0; j < 4; ++j) b0[j] = ldB(cur, j, 0);
    stageB(nxt, 1, tn1);
    __builtin_amdgcn_s_barrier();
    asm volatile("s_waitcnt lgkmcnt(0)" ::: "memory");
    __builtin_amdgcn_sched_barrier(0);
    __builtin_amdgcn_s_setprio(1);
#pragma unroll
    for (int i = 0; i < 4; ++i)
#pragma unroll
      for (int j = 0; j < 4; ++j) acc[i][j] = mfma16(a0[i], b0[j], acc[i][j]);
    __builtin_amdgcn_s_setprio(0);
    __builtin_amdgcn_s_barrier();

    // ---- ph2: (Mhalf0, kc1) ----
#pragma unroll
    for (int i = 0; i < 4; ++i) a0[i] = ldA(cur, i, 1);
#pragma unroll
    for (int j = 0; j < 4; ++j) b1[j] = ldB(cur, j, 1);
    stageA(nxt, 1, tn1);
    __builtin_amdgcn_s_barrier();
    asm volatile("s_waitcnt lgkmcnt(0)" ::: "memory");
    __builtin_amdgcn_sched_barrier(0);
    __builtin_amdgcn_s_setprio(1);
#pragma unroll
    for (int i = 0; i < 4; ++i)
#pragma unroll
      for (int j = 0; j < 4; ++j) acc[i][j] = mfma16(a0[i], b1[j], acc[i][j]);
    __builtin_amdgcn_s_setprio(0);
    asm volatile("s_waitcnt vmcnt(8)" ::: "memory");
    __builtin_amdgcn_s_barrier();

    // ---- ph3: (Mhalf1, kc0) ----
#pragma unroll
    for (int i = 0; i < 4; ++i) a0[i] = ldA(cur, 4 + i, 0);
    stageA(cur, 0, tn2);
    __builtin_amdgcn_s_barrier();
    asm volatile("s_waitcnt lgkmcnt(0)" ::: "memory");
    __builtin_amdgcn_sched_barrier(0);
    __builtin_amdgcn_s_setprio(1);
#pragma unroll
    for (int i = 0; i < 4; ++i)
#pragma unroll
      for (int j = 0; j < 4; ++j) acc[4 + i][j] = mfma16(a0[i], b0[j], acc[4 + i][j]);
    __builtin_amdgcn_s_setprio(0);
    __builtin_amdgcn_s_barrier();

    // ---- ph4: (Mhalf1, kc1) ----
#pragma unroll
    for (int i = 0; i < 4; ++i) a0[i] = ldA(cur, 4 + i, 1);
    stageB(cur, 0, tn2);
    __builtin_amdgcn_s_barrier();
    asm volatile("s_waitcnt lgkmcnt(0)" ::: "memory");
    __builtin_amdgcn_sched_barrier(0);
    __builtin_amdgcn_s_setprio(1);
#pragma unroll
    for (int i = 0; i < 4; ++i)
#pragma unroll
      for (int j = 0; j < 4; ++j) acc[4 + i][j] = mfma16(a0[i], b1[j], acc[4 + i][j]);
    __builtin_amdgcn_s_setprio(0);
    asm volatile("s_waitcnt vmcnt(6)" ::: "memory");
    __builtin_amdgcn_s_barrier();
  }

  // epilogue
#pragma unroll
  for (int mi = 0; mi < 8; ++mi) {
    int row = bm + wr * 128 + mi * 16 + g * 4;
#pragma unroll
    for (int j = 0; j < 4; ++j) {
      int col = bn + wc * 64 + j * 16 + l15;
      float bcv = biasCol ? biasCol[col] : 0.0f;
#pragma unroll
      for (int rr = 0; rr < 4; ++rr) {
        float brv = biasRow ? biasRow[row + rr] : 0.0f;
        float v = acc[mi][j][rr] + bcv + brv;
        if constexpr (sizeof(CT) == 2)
          C[(size_t)(row + rr) * ldc + col] = f2bf(v);
        else
          C[(size_t)(row + rr) * ldc + col] = v;
      }
    }
  }
}

// ---- merged projection dispatch: z=0 Q, z=1 K, z=2 V^T  (384 blocks) ----
__global__ __launch_bounds__(512, 2) void proj3(
    const u16* __restrict__ prim_ctx,   // prim_bf ++ ctx_bf   [2][8192][1024]
    const u16* __restrict__ wqk,        // wqt ++ wkt          [2][1024][1024]
    const u16* __restrict__ wvt,        // [1024][1024]
    const u16* __restrict__ ctx_bf,     // [8192][1024]
    const float* __restrict__ bq, const float* __restrict__ bk,
    const float* __restrict__ bv,
    u16* __restrict__ qk,               // qbf ++ kbf          [2][8192][1024]
    u16* __restrict__ vt) {             // [1024][8192]
  int bz = blockIdx.z;
  if (bz < 2) {
    // Q or K: A[8192x1024] * W^T + bias(col)
    gemm_body<u16>(prim_ctx + (size_t)bz * 8192 * 1024,
                   wqk + (size_t)bz * 1024 * 1024,
                   bz ? bk : bq, nullptr,
                   qk + (size_t)bz * 8192 * 1024,
                   blockIdx.x * 256, blockIdx.y * 256, 1024, 1024, 1024, 1024);
  } else {
    // V^T: wvt[1024x1024] * ctx^T + bv(row) -> vt[1024x8192]
    int lin = blockIdx.x + 32 * blockIdx.y;   // 0..127
    int vx = lin & 3, vy = lin >> 2;          // vx<4, vy<32
    gemm_body<u16>(wvt, ctx_bf, nullptr, bv, vt,
                   vx * 256, vy * 256, 1024, 1024, 1024, 8192);
  }
}

// ---- generic batched GEMM (S and PV) ----
template <typename CT>
__global__ __launch_bounds__(512, 2) void gemm256(
    const u16* __restrict__ A, const u16* __restrict__ Bt,
    CT* __restrict__ C, int K, int lda, int ldb, int ldc,
    long long bsA, long long bsB, long long bsC) {
  gemm_body<CT>(A + (size_t)blockIdx.z * bsA, Bt + (size_t)blockIdx.z * bsB,
                nullptr, nullptr, C + (size_t)blockIdx.z * bsC,
                blockIdx.x * 256, blockIdx.y * 256, K, lda, ldb, ldc);
}

// ---------------- fused mask + row softmax ----------------
__global__ __launch_bounds__(256) void softmax_mask(
    const u16* __restrict__ S, const float* __restrict__ mask, u16* __restrict__ P) {
  const float C1 = 0.04508422f;    // log2(e)/32
  const float C2 = -1.4426950e9f;  // -1e9*log2(e)
  int wid = (blockIdx.x * blockDim.x + threadIdx.x) >> 6;  // global wave = row
  int lane = threadIdx.x & 63;
  size_t base = (size_t)wid * 2048;
  const u16* sp = S + base;
  const float* mp = mask + base;

  float a[32];
#pragma unroll
  for (int pass = 0; pass < 4; ++pass) {
    int e0 = pass * 512 + lane * 8;
    u16x8 sv = *(const u16x8*)(sp + e0);
    float4 m0 = *(const float4*)(mp + e0);
    float4 m1 = *(const float4*)(mp + e0 + 4);
    a[pass * 8 + 0] = bf2f(sv[0]) * C1 + m0.x * C2;
    a[pass * 8 + 1] = bf2f(sv[1]) * C1 + m0.y * C2;
    a[pass * 8 + 2] = bf2f(sv[2]) * C1 + m0.z * C2;
    a[pass * 8 + 3] = bf2f(sv[3]) * C1 + m0.w * C2;
    a[pass * 8 + 4] = bf2f(sv[4]) * C1 + m1.x * C2;
    a[pass * 8 + 5] = bf2f(sv[5]) * C1 + m1.y * C2;
    a[pass * 8 + 6] = bf2f(sv[6]) * C1 + m1.z * C2;
    a[pass * 8 + 7] = bf2f(sv[7]) * C1 + m1.w * C2;
  }
  float m = a[0];
#pragma unroll
  for (int i = 1; i < 32; ++i) m = fmaxf(m, a[i]);
#pragma unroll
  for (int off = 32; off >= 1; off >>= 1) m = fmaxf(m, __shfl_xor(m, off));

  float s = 0.0f;
#pragma unroll
  for (int i = 0; i < 32; ++i) {
    a[i] = exp2f(a[i] - m);
    s += a[i];
  }
#pragma unroll
  for (int off = 32; off >= 1; off >>= 1) s += __shfl_xor(s, off);
  float inv = 1.0f / s;

  u16* pp = P + base;
#pragma unroll
  for (int pass = 0; pass < 4; ++pass) {
    int e0 = pass * 512 + lane * 8;
    u16x8 o;
#pragma unroll
    for (int j = 0; j < 8; ++j) o[j] = f2bf(a[pass * 8 + j] * inv);
    *(u16x8*)(pp + e0) = o;
  }
}

extern "C" void kernel_launch(void* const* d_in, const int* in_sizes, int n_in,
                              void* d_out, int out_size, void* d_ws, size_t ws_size,
                              hipStream_t stream) {
  const float* primary = (const float*)d_in[0];
  const float* ctx     = (const float*)d_in[1];
  const float* mask    = (const float*)d_in[2];
  const float* Wq      = (const float*)d_in[3];
  const float* bq      = (const float*)d_in[4];
  const float* Wk      = (const float*)d_in[5];
  const float* bk      = (const float*)d_in[6];
  const float* Wv      = (const float*)d_in[7];
  const float* bv      = (const float*)d_in[8];
  float* out = (float*)d_out;

  char* ws = (char*)d_ws;
  // Layout (peak 90.2 MB):
  //   [0, 16.7M)    qbf      } P overlays [0, 33.5M)
  //   [16.7, 33.5M) kbf      }
  //   [33.5, 50.3M) vtbf
  //   [50.3, 67M)   prim_bf  } S bf16 overlays [50.3, 83.9M)
  //   [67, 83.9M)   ctx_bf   }
  //   [83.9, 90.2M) wqt/wkt/wvt   (wqt,wkt contiguous)
  u16* qbf     = (u16*)(ws);
  u16* kbf     = (u16*)(ws + 16777216);
  u16* vtbf    = (u16*)(ws + 2 * 16777216);
  u16* prim_bf = (u16*)(ws + 3 * 16777216);
  u16* ctx_bf  = (u16*)(ws + 4 * 16777216);
  u16* wqt     = (u16*)(ws + 5 * 16777216);
  u16* wkt     = (u16*)(ws + 5 * 16777216 + 2097152);
  u16* wvt     = (u16*)(ws + 5 * 16777216 + 2 * 2097152);
  u16* sbf     = (u16*)(ws + 3 * 16777216);
  u16* pbf     = (u16*)(ws);

  // converts + weight transposes, one dispatch
  cvt_wt<<<5120, 256, 0, stream>>>(primary, prim_bf, ctx, ctx_bf,
                                   Wq, Wk, Wv, wqt, wkt, wvt);
  // Q, K, V^T projections, one dispatch (384 blocks)
  proj3<<<dim3(32, 4, 3), 512, 0, stream>>>(
      prim_bf, wqt, wvt, ctx_bf, bq, bk, bv, qbf, vtbf);
  // S = Q @ K^T -> sbf [4][2048 x 2048] bf16
  gemm256<u16><<<dim3(8, 8, 4), 512, 0, stream>>>(
      qbf, kbf, sbf, 1024, 1024, 1024, 2048,
      2048 * 1024LL, 2048 * 1024LL, 2048 * 2048LL);
  // P = softmax(S*C1 + mask*C2) -> pbf
  softmax_mask<<<2048, 256, 0, stream>>>(sbf, mask, pbf);
  // O = P @ (V^T)^T -> out fp32 [4][2048 x 1024]
  gemm256<float><<<dim3(8, 4, 4), 512, 0, stream>>>(
      pbf, vtbf, out, 2048, 2048, 8192, 1024,
      2048 * 2048LL, 2048LL, 2048 * 1024LL);
}